// Round 1
// baseline (460.315 us; speedup 1.0000x reference)
//
#include <hip/hip_runtime.h>

typedef unsigned short u16;
typedef unsigned int u32;
typedef __attribute__((ext_vector_type(4))) float f32x4;
typedef __attribute__((ext_vector_type(8))) short bf16x8;
typedef __attribute__((ext_vector_type(8))) u16 u16x8;

// ---- helpers ----
__device__ __forceinline__ u16 f2b(float f) {
  union { float f; u32 u; } v; v.f = f;
  u32 r = v.u + 0x7FFFu + ((v.u >> 16) & 1u);
  return (u16)(r >> 16);
}
__device__ __forceinline__ float b2f(u16 h) {
  union { u32 u; float f; } v; v.u = ((u32)h) << 16;
  return v.f;
}
__device__ __forceinline__ void gload_lds16(const void* g, void* lds) {
  __builtin_amdgcn_global_load_lds(
      (__attribute__((address_space(1))) void*)(void*)g,
      (__attribute__((address_space(3))) void*)lds, 16, 0, 0);
}

// ---- cast x (fp32 -> bf16), vectorized 8/thread ----
__global__ __launch_bounds__(256) void cast_x_kernel(const float* __restrict__ x,
                                                     u16* __restrict__ xb, size_t n8) {
  size_t i = (size_t)blockIdx.x * blockDim.x + threadIdx.x;
  size_t stride = (size_t)gridDim.x * blockDim.x;
  for (; i < n8; i += stride) {
    const float4* p = (const float4*)(x + i * 8);
    float4 a = p[0], b = p[1];
    u16x8 o;
    o[0] = f2b(a.x); o[1] = f2b(a.y); o[2] = f2b(a.z); o[3] = f2b(a.w);
    o[4] = f2b(b.x); o[5] = f2b(b.y); o[6] = f2b(b.z); o[7] = f2b(b.w);
    *(u16x8*)(xb + i * 8) = o;
  }
}

// ---- transpose + cast: W[R][C] (fp32) -> WT[C][R] (bf16) ----
__global__ __launch_bounds__(256) void transpose_cast_kernel(const float* __restrict__ W,
                                                             u16* __restrict__ WT,
                                                             int R, int C) {
  __shared__ u16 tile[32][33];
  int rt = R >> 5;
  int tr = blockIdx.x % rt, tc = blockIdx.x / rt;
  int r0 = tr * 32, c0 = tc * 32;
#pragma unroll
  for (int i = 0; i < 4; ++i) {
    int r = (threadIdx.x >> 5) + i * 8, c = threadIdx.x & 31;
    tile[r][c] = f2b(W[(size_t)(r0 + r) * C + c0 + c]);
  }
  __syncthreads();
#pragma unroll
  for (int i = 0; i < 4; ++i) {
    int c = (threadIdx.x >> 5) + i * 8, r = threadIdx.x & 31;
    WT[(size_t)(c0 + c) * R + r0 + r] = tile[r][c];
  }
}

// ---- GEMM: C[M][N] = A[M][K] * BT[N][K]^T, bf16 in, fp32 acc ----
// 128x128 tile, BK=32, 4 waves (2x2 of 64x64), 16x16x32 bf16 MFMA.
template <bool OUT_BF16, bool BIAS>
__global__ __launch_bounds__(256) void gemm_bt_kernel(const u16* __restrict__ A,
                                                      const u16* __restrict__ BT,
                                                      void* __restrict__ Cv,
                                                      const float* __restrict__ bias,
                                                      int M, int N, int K) {
  (void)M;
  __shared__ u16 As[128 * 32];
  __shared__ u16 Bs[128 * 32];
  const int ntile = N >> 7;
  const int tm = blockIdx.x / ntile, tn = blockIdx.x % ntile;
  const int tid = threadIdx.x;
  const int wave = tid >> 6, lane = tid & 63;
  const int wr = wave >> 1, wc = wave & 1;
  const int lr = lane & 15, lk = (lane >> 4) << 3;

  f32x4 acc[4][4] = {};
  const size_t rowA0 = (size_t)tm * 128;
  const size_t rowB0 = (size_t)tn * 128;

  for (int kk = 0; kk < K; kk += 32) {
#pragma unroll
    for (int it = 0; it < 2; ++it) {
      int u = it * 256 + tid;         // 16B unit index, 0..511
      int r = u >> 2, c8 = (u & 3) * 8;
      gload_lds16(A + (rowA0 + r) * K + kk + c8, &As[(it * 256 + wave * 64) * 8]);
      gload_lds16(BT + (rowB0 + r) * K + kk + c8, &Bs[(it * 256 + wave * 64) * 8]);
    }
    __syncthreads();
    bf16x8 af[4], bfv[4];
#pragma unroll
    for (int i = 0; i < 4; ++i)
      af[i] = *(const bf16x8*)&As[(wr * 64 + i * 16 + lr) * 32 + lk];
#pragma unroll
    for (int j = 0; j < 4; ++j)
      bfv[j] = *(const bf16x8*)&Bs[(wc * 64 + j * 16 + lr) * 32 + lk];
#pragma unroll
    for (int i = 0; i < 4; ++i)
#pragma unroll
      for (int j = 0; j < 4; ++j)
        acc[i][j] = __builtin_amdgcn_mfma_f32_16x16x32_bf16(af[i], bfv[j], acc[i][j], 0, 0, 0);
    __syncthreads();
  }

  const int orow = tm * 128 + wr * 64;
  const int ocol = tn * 128 + wc * 64;
#pragma unroll
  for (int i = 0; i < 4; ++i)
#pragma unroll
    for (int j = 0; j < 4; ++j) {
      int col = ocol + j * 16 + lr;
      float bv = BIAS ? bias[col] : 0.0f;
#pragma unroll
      for (int q = 0; q < 4; ++q) {
        int row = orow + i * 16 + ((lane >> 4) * 4 + q);
        float v = acc[i][j][q] + bv;
        if (OUT_BF16) ((u16*)Cv)[(size_t)row * N + col] = f2b(v);
        else          ((float*)Cv)[(size_t)row * N + col] = v;
      }
    }
}

// ---- softmax over 64 contiguous bf16 (q,k chunks of qkv), in place ----
__global__ __launch_bounds__(256) void softmax64_kernel(u16* __restrict__ qkv, int nchunks) {
  int gw = ((int)(blockIdx.x * blockDim.x + threadIdx.x)) >> 6;
  int lane = threadIdx.x & 63;
  int nw = (gridDim.x * blockDim.x) >> 6;
  for (int c = gw; c < nchunks; c += nw) {
    int row = c / 24, chunk = c % 24;   // chunks 0..23 -> cols [0,1536) = q,k
    size_t idx = (size_t)row * 2304 + chunk * 64 + lane;
    float v = b2f(qkv[idx]);
    float m = v;
#pragma unroll
    for (int s = 32; s > 0; s >>= 1) m = fmaxf(m, __shfl_xor(m, s, 64));
    float e = __expf(v - m);
    float sum = e;
#pragma unroll
    for (int s = 32; s > 0; s >>= 1) sum += __shfl_xor(sum, s, 64);
    qkv[idx] = f2b(e / sum);
  }
}

// ---- context partials: partial[sp][bh][d][e] = sum_{n in split} k[n,d]*v[n,e] ----
#define NS 8
__global__ __launch_bounds__(256) void ctx_partial_kernel(const u16* __restrict__ qkv,
                                                          float* __restrict__ partial) {
  __shared__ u16 kT[64 * 136];
  __shared__ u16 vT[64 * 136];
  int bh = blockIdx.x / NS, sp = blockIdx.x % NS;
  int b = bh / 12, h = bh % 12;
  int tid = threadIdx.x, wave = tid >> 6, lane = tid & 63;
  int lr = lane & 15, lk = (lane >> 4) << 3;
  f32x4 acc[4] = {};
  int baseK = 768 + h * 64, baseV = 1536 + h * 64;

  for (int sub = 0; sub < 4; ++sub) {
    int nbase = b * 4096 + sp * 512 + sub * 128;
    __syncthreads();
#pragma unroll
    for (int it = 0; it < 4; ++it) {
      int s = it * 256 + tid;          // 0..1023 segments of 8 elems
      int n = s >> 3, c8 = (s & 7) * 8;
      u16x8 kv = *(const u16x8*)(qkv + (size_t)(nbase + n) * 2304 + baseK + c8);
      u16x8 vv = *(const u16x8*)(qkv + (size_t)(nbase + n) * 2304 + baseV + c8);
#pragma unroll
      for (int q = 0; q < 8; ++q) {
        kT[(c8 + q) * 136 + n] = kv[q];
        vT[(c8 + q) * 136 + n] = vv[q];
      }
    }
    __syncthreads();
#pragma unroll
    for (int ks = 0; ks < 4; ++ks) {
      bf16x8 af = *(const bf16x8*)&kT[(wave * 16 + lr) * 136 + ks * 32 + lk];
#pragma unroll
      for (int jt = 0; jt < 4; ++jt) {
        bf16x8 bfv = *(const bf16x8*)&vT[(jt * 16 + lr) * 136 + ks * 32 + lk];
        acc[jt] = __builtin_amdgcn_mfma_f32_16x16x32_bf16(af, bfv, acc[jt], 0, 0, 0);
      }
    }
  }
  float* dst = partial + ((size_t)sp * 96 + bh) * 4096;
#pragma unroll
  for (int jt = 0; jt < 4; ++jt)
#pragma unroll
    for (int q = 0; q < 4; ++q) {
      int d = wave * 16 + (lane >> 4) * 4 + q;
      int e = jt * 16 + lr;
      dst[d * 64 + e] = acc[jt][q];
    }
}

// ---- reduce partials -> ctxT[bh][e][d] bf16 ----
__global__ __launch_bounds__(256) void ctx_reduce_kernel(const float* __restrict__ partial,
                                                         u16* __restrict__ ctxT) {
  int idx = blockIdx.x * 256 + threadIdx.x;   // 96*4096
  int bh = idx >> 12;
  int e = (idx >> 6) & 63, d = idx & 63;
  float s = 0.0f;
#pragma unroll
  for (int sp = 0; sp < NS; ++sp) s += partial[((size_t)sp * 96 + bh) * 4096 + d * 64 + e];
  ctxT[(size_t)bh * 4096 + e * 64 + d] = f2b(s);
}

// ---- attn[b*4096+n][h*64+e] = sum_d q[n,d]*ctx[d,e]  (bf16 out) ----
__global__ __launch_bounds__(256) void attn_kernel(const u16* __restrict__ qkv,
                                                   const u16* __restrict__ ctxT,
                                                   u16* __restrict__ attn) {
  __shared__ u16 qs[128 * 64];
  __shared__ u16 cs[64 * 64];
  int bh = blockIdx.x >> 5, nt = blockIdx.x & 31;
  int b = bh / 12, h = bh % 12;
  int tid = threadIdx.x, wave = tid >> 6, lane = tid & 63;
  int lr = lane & 15, lk = (lane >> 4) << 3;
  int row0 = b * 4096 + nt * 128;
#pragma unroll
  for (int it = 0; it < 4; ++it) {
    int u = it * 256 + tid;
    int n = u >> 3, c8 = (u & 7) * 8;
    gload_lds16(qkv + (size_t)(row0 + n) * 2304 + h * 64 + c8, &qs[(it * 256 + wave * 64) * 8]);
  }
#pragma unroll
  for (int it = 0; it < 2; ++it) {
    int u = it * 256 + tid;
    gload_lds16(ctxT + (size_t)bh * 4096 + u * 8, &cs[(it * 256 + wave * 64) * 8]);
  }
  __syncthreads();
  f32x4 acc[2][4] = {};
#pragma unroll
  for (int ks = 0; ks < 2; ++ks) {
    bf16x8 bv[4];
#pragma unroll
    for (int jt = 0; jt < 4; ++jt) bv[jt] = *(const bf16x8*)&cs[(jt * 16 + lr) * 64 + ks * 32 + lk];
#pragma unroll
    for (int i = 0; i < 2; ++i) {
      bf16x8 af = *(const bf16x8*)&qs[(wave * 32 + i * 16 + lr) * 64 + ks * 32 + lk];
#pragma unroll
      for (int jt = 0; jt < 4; ++jt)
        acc[i][jt] = __builtin_amdgcn_mfma_f32_16x16x32_bf16(af, bv[jt], acc[i][jt], 0, 0, 0);
    }
  }
#pragma unroll
  for (int i = 0; i < 2; ++i)
#pragma unroll
    for (int jt = 0; jt < 4; ++jt)
#pragma unroll
      for (int q = 0; q < 4; ++q) {
        int n = nt * 128 + wave * 32 + i * 16 + (lane >> 4) * 4 + q;
        int col = h * 64 + jt * 16 + lr;
        attn[(size_t)(b * 4096 + n) * 768 + col] = f2b(acc[i][jt][q]);
      }
}

extern "C" void kernel_launch(void* const* d_in, const int* in_sizes, int n_in,
                              void* d_out, int out_size, void* d_ws, size_t ws_size,
                              hipStream_t stream) {
  const float* x = (const float*)d_in[0];
  const float* Wqkv = (const float*)d_in[1];
  const float* Wproj = (const float*)d_in[2];
  const float* bproj = (const float*)d_in[3];
  float* out = (float*)d_out;
  char* ws = (char*)d_ws;

  // ws layout (bytes): total ~257.3 MiB
  u16* xb     = (u16*)(ws);                      // 32768*768*2   = 50331648
  u16* WqkvT  = (u16*)(ws + 50331648);           // 2304*768*2    = 3538944
  u16* WprojT = (u16*)(ws + 53870592);           // 768*768*2     = 1179648
  u16* qkv    = (u16*)(ws + 55050240);           // 32768*2304*2  = 150994944
  float* partial = (float*)(ws + 206045184);     // 8*96*4096*4   = 12582912
  u16* ctxT   = (u16*)(ws + 218628096);          // 96*4096*2     = 786432
  u16* attn   = (u16*)(ws + 219414528);          // 32768*768*2   = 50331648

  cast_x_kernel<<<2048, 256, 0, stream>>>(x, xb, (size_t)(32768ll * 768 / 8));
  transpose_cast_kernel<<<(768 / 32) * (2304 / 32), 256, 0, stream>>>(Wqkv, WqkvT, 768, 2304);
  transpose_cast_kernel<<<(768 / 32) * (768 / 32), 256, 0, stream>>>(Wproj, WprojT, 768, 768);

  gemm_bt_kernel<true, false><<<(32768 / 128) * (2304 / 128), 256, 0, stream>>>(
      xb, WqkvT, (void*)qkv, nullptr, 32768, 2304, 768);

  softmax64_kernel<<<2048, 256, 0, stream>>>(qkv, 32768 * 24);

  ctx_partial_kernel<<<96 * NS, 256, 0, stream>>>(qkv, partial);
  ctx_reduce_kernel<<<(96 * 4096) / 256, 256, 0, stream>>>(partial, ctxT);

  attn_kernel<<<96 * 32, 256, 0, stream>>>(qkv, ctxT, attn);

  gemm_bt_kernel<false, true><<<(32768 / 128) * (768 / 128), 256, 0, stream>>>(
      attn, WprojT, (void*)out, bproj, 32768, 768, 768);
}

// Round 2
// 342.689 us; speedup vs baseline: 1.3432x; 1.3432x over previous
//
#include <hip/hip_runtime.h>

typedef unsigned short u16;
typedef unsigned int u32;
typedef __attribute__((ext_vector_type(4))) float f32x4;
typedef __attribute__((ext_vector_type(8))) short bf16x8;
typedef __attribute__((ext_vector_type(8))) u16 u16x8;

// ---- helpers ----
__device__ __forceinline__ u16 f2b(float f) {
  union { float f; u32 u; } v; v.f = f;
  u32 r = v.u + 0x7FFFu + ((v.u >> 16) & 1u);
  return (u16)(r >> 16);
}
__device__ __forceinline__ float b2f(u16 h) {
  union { u32 u; float f; } v; v.u = ((u32)h) << 16;
  return v.f;
}
__device__ __forceinline__ void gload_lds16(const void* g, void* lds) {
  __builtin_amdgcn_global_load_lds(
      (__attribute__((address_space(1))) void*)(void*)g,
      (__attribute__((address_space(3))) void*)lds, 16, 0, 0);
}

// ---- cast x (fp32 -> bf16), vectorized 8/thread ----
__global__ __launch_bounds__(256) void cast_x_kernel(const float* __restrict__ x,
                                                     u16* __restrict__ xb, size_t n8) {
  size_t i = (size_t)blockIdx.x * blockDim.x + threadIdx.x;
  size_t stride = (size_t)gridDim.x * blockDim.x;
  for (; i < n8; i += stride) {
    const float4* p = (const float4*)(x + i * 8);
    float4 a = p[0], b = p[1];
    u16x8 o;
    o[0] = f2b(a.x); o[1] = f2b(a.y); o[2] = f2b(a.z); o[3] = f2b(a.w);
    o[4] = f2b(b.x); o[5] = f2b(b.y); o[6] = f2b(b.z); o[7] = f2b(b.w);
    *(u16x8*)(xb + i * 8) = o;
  }
}

// ---- transpose + cast: W[R][C] (fp32) -> WT[C][R] (bf16) ----
__global__ __launch_bounds__(256) void transpose_cast_kernel(const float* __restrict__ W,
                                                             u16* __restrict__ WT,
                                                             int R, int C) {
  __shared__ u16 tile[32][33];
  int rt = R >> 5;
  int tr = blockIdx.x % rt, tc = blockIdx.x / rt;
  int r0 = tr * 32, c0 = tc * 32;
#pragma unroll
  for (int i = 0; i < 4; ++i) {
    int r = (threadIdx.x >> 5) + i * 8, c = threadIdx.x & 31;
    tile[r][c] = f2b(W[(size_t)(r0 + r) * C + c0 + c]);
  }
  __syncthreads();
#pragma unroll
  for (int i = 0; i < 4; ++i) {
    int c = (threadIdx.x >> 5) + i * 8, r = threadIdx.x & 31;
    WT[(size_t)(c0 + c) * R + r0 + r] = tile[r][c];
  }
}

// ================= 256x256 phase-pipelined GEMM =================
// C[M][N] = A[M][K] * BT[N][K]^T ; bf16 in, fp32 acc.
// BM=BN=256, BK=32, 512 thr (8 waves, 2Mx4N), per-wave out 128x64.
// LDS: 4-deep ring of (A 16KB + B 16KB) = 128 KB; prefetch distance 3;
// counted vmcnt(8) per K-tile; col16 ^= (row&3) swizzle (both sides).
#define BM 256
#define BN 256
#define BK 32

template <bool OUT_BF16, bool BIAS, bool SOFTMAX>
__global__ __launch_bounds__(512, 2) void gemm256_kernel(
    const u16* __restrict__ A, const u16* __restrict__ BT, void* __restrict__ Cv,
    const float* __restrict__ bias, int M, int N, int K, int ntile) {
  (void)M;
  __shared__ u16 As[4 * 8192];
  __shared__ u16 Bs[4 * 8192];
  const int tid = threadIdx.x;
  const int wave = tid >> 6, lane = tid & 63;
  const int lr = lane & 15, hi = lane >> 4;
  const int wr = wave >> 2, wc = wave & 3;

  // bijective XCD swizzle (grid % 8 == 0)
  const int cpx = gridDim.x >> 3;
  const int wg = (blockIdx.x & 7) * cpx + (blockIdx.x >> 3);
  const int tm = wg / ntile, tn = wg % ntile;

  const size_t rowA0 = (size_t)tm * BM;
  const size_t rowB0 = (size_t)tn * BN;

  // staging: thread covers LDS rows rA, rA+128 (linear dest); source col16
  // pre-swizzled so that LDS slot (r,c) holds global (r, c^(r&3)).
  const int rA = wave * 16 + (lane >> 2);          // 0..127
  const int csw = (lane & 3) ^ (rA & 3);           // swizzled col16 of source
  const u16* srcA = A + (rowA0 + rA) * K + (csw << 3);
  const u16* srcB = BT + (rowB0 + rA) * K + (csw << 3);
  const int dstw = wave * 512;                     // u16 offset within tile buf

  const int NT = K / BK;

  // read-side: logical (row, hi) lives at LDS (row, hi^(row&3))
  const int xs = ((hi ^ (lr & 3)) << 3);
  const int arow = wr * 128 + lr;
  const int brow = wc * 64 + lr;

  f32x4 acc[8][4] = {};

  // prologue: stage tiles 0..2 (12 loads/thread outstanding)
#pragma unroll
  for (int pt = 0; pt < 3; ++pt) {
    u16* Ad = &As[pt * 8192 + dstw];
    u16* Bd = &Bs[pt * 8192 + dstw];
    const u16* sa = srcA + pt * BK;
    const u16* sb = srcB + pt * BK;
    gload_lds16(sa, Ad);
    gload_lds16(sa + (size_t)128 * K, Ad + 4096);
    gload_lds16(sb, Bd);
    gload_lds16(sb + (size_t)128 * K, Bd + 4096);
  }
  asm volatile("s_waitcnt vmcnt(8)" ::: "memory");   // tile 0 landed
  __builtin_amdgcn_sched_barrier(0);
  __builtin_amdgcn_s_barrier();

  for (int t = 0; t < NT; ++t) {
    const u16* Ab = &As[(t & 3) * 8192];
    const u16* Bb = &Bs[(t & 3) * 8192];
    const int tp = t + 3;
    const bool do_stage = tp < NT;
    const u16* sa = srcA + tp * BK;
    const u16* sb = srcB + tp * BK;
    u16* Ad = &As[(tp & 3) * 8192 + dstw];
    u16* Bd = &Bs[(tp & 3) * 8192 + dstw];

    // ---- phase 1: read a-half0 + all b, stage A(t+3), MFMA quadrant
    bf16x8 a0 = *(const bf16x8*)&Ab[(arow + 0) * 32 + xs];
    bf16x8 a1 = *(const bf16x8*)&Ab[(arow + 16) * 32 + xs];
    bf16x8 a2 = *(const bf16x8*)&Ab[(arow + 32) * 32 + xs];
    bf16x8 a3 = *(const bf16x8*)&Ab[(arow + 48) * 32 + xs];
    bf16x8 b0 = *(const bf16x8*)&Bb[(brow + 0) * 32 + xs];
    bf16x8 b1 = *(const bf16x8*)&Bb[(brow + 16) * 32 + xs];
    bf16x8 b2 = *(const bf16x8*)&Bb[(brow + 32) * 32 + xs];
    bf16x8 b3 = *(const bf16x8*)&Bb[(brow + 48) * 32 + xs];
    if (do_stage) {
      gload_lds16(sa, Ad);
      gload_lds16(sa + (size_t)128 * K, Ad + 4096);
    }
    __builtin_amdgcn_s_barrier();
    asm volatile("s_waitcnt lgkmcnt(0)" ::: "memory");
    __builtin_amdgcn_sched_barrier(0);
    __builtin_amdgcn_s_setprio(1);
    acc[0][0] = __builtin_amdgcn_mfma_f32_16x16x32_bf16(a0, b0, acc[0][0], 0, 0, 0);
    acc[0][1] = __builtin_amdgcn_mfma_f32_16x16x32_bf16(a0, b1, acc[0][1], 0, 0, 0);
    acc[0][2] = __builtin_amdgcn_mfma_f32_16x16x32_bf16(a0, b2, acc[0][2], 0, 0, 0);
    acc[0][3] = __builtin_amdgcn_mfma_f32_16x16x32_bf16(a0, b3, acc[0][3], 0, 0, 0);
    acc[1][0] = __builtin_amdgcn_mfma_f32_16x16x32_bf16(a1, b0, acc[1][0], 0, 0, 0);
    acc[1][1] = __builtin_amdgcn_mfma_f32_16x16x32_bf16(a1, b1, acc[1][1], 0, 0, 0);
    acc[1][2] = __builtin_amdgcn_mfma_f32_16x16x32_bf16(a1, b2, acc[1][2], 0, 0, 0);
    acc[1][3] = __builtin_amdgcn_mfma_f32_16x16x32_bf16(a1, b3, acc[1][3], 0, 0, 0);
    acc[2][0] = __builtin_amdgcn_mfma_f32_16x16x32_bf16(a2, b0, acc[2][0], 0, 0, 0);
    acc[2][1] = __builtin_amdgcn_mfma_f32_16x16x32_bf16(a2, b1, acc[2][1], 0, 0, 0);
    acc[2][2] = __builtin_amdgcn_mfma_f32_16x16x32_bf16(a2, b2, acc[2][2], 0, 0, 0);
    acc[2][3] = __builtin_amdgcn_mfma_f32_16x16x32_bf16(a2, b3, acc[2][3], 0, 0, 0);
    acc[3][0] = __builtin_amdgcn_mfma_f32_16x16x32_bf16(a3, b0, acc[3][0], 0, 0, 0);
    acc[3][1] = __builtin_amdgcn_mfma_f32_16x16x32_bf16(a3, b1, acc[3][1], 0, 0, 0);
    acc[3][2] = __builtin_amdgcn_mfma_f32_16x16x32_bf16(a3, b2, acc[3][2], 0, 0, 0);
    acc[3][3] = __builtin_amdgcn_mfma_f32_16x16x32_bf16(a3, b3, acc[3][3], 0, 0, 0);
    __builtin_amdgcn_s_setprio(0);
    __builtin_amdgcn_s_barrier();

    // ---- phase 2: read a-half1, stage B(t+3), MFMA quadrant
    a0 = *(const bf16x8*)&Ab[(arow + 64) * 32 + xs];
    a1 = *(const bf16x8*)&Ab[(arow + 80) * 32 + xs];
    a2 = *(const bf16x8*)&Ab[(arow + 96) * 32 + xs];
    a3 = *(const bf16x8*)&Ab[(arow + 112) * 32 + xs];
    if (do_stage) {
      gload_lds16(sb, Bd);
      gload_lds16(sb + (size_t)128 * K, Bd + 4096);
    }
    __builtin_amdgcn_s_barrier();
    asm volatile("s_waitcnt lgkmcnt(0)" ::: "memory");
    __builtin_amdgcn_sched_barrier(0);
    __builtin_amdgcn_s_setprio(1);
    acc[4][0] = __builtin_amdgcn_mfma_f32_16x16x32_bf16(a0, b0, acc[4][0], 0, 0, 0);
    acc[4][1] = __builtin_amdgcn_mfma_f32_16x16x32_bf16(a0, b1, acc[4][1], 0, 0, 0);
    acc[4][2] = __builtin_amdgcn_mfma_f32_16x16x32_bf16(a0, b2, acc[4][2], 0, 0, 0);
    acc[4][3] = __builtin_amdgcn_mfma_f32_16x16x32_bf16(a0, b3, acc[4][3], 0, 0, 0);
    acc[5][0] = __builtin_amdgcn_mfma_f32_16x16x32_bf16(a1, b0, acc[5][0], 0, 0, 0);
    acc[5][1] = __builtin_amdgcn_mfma_f32_16x16x32_bf16(a1, b1, acc[5][1], 0, 0, 0);
    acc[5][2] = __builtin_amdgcn_mfma_f32_16x16x32_bf16(a1, b2, acc[5][2], 0, 0, 0);
    acc[5][3] = __builtin_amdgcn_mfma_f32_16x16x32_bf16(a1, b3, acc[5][3], 0, 0, 0);
    acc[6][0] = __builtin_amdgcn_mfma_f32_16x16x32_bf16(a2, b0, acc[6][0], 0, 0, 0);
    acc[6][1] = __builtin_amdgcn_mfma_f32_16x16x32_bf16(a2, b1, acc[6][1], 0, 0, 0);
    acc[6][2] = __builtin_amdgcn_mfma_f32_16x16x32_bf16(a2, b2, acc[6][2], 0, 0, 0);
    acc[6][3] = __builtin_amdgcn_mfma_f32_16x16x32_bf16(a2, b3, acc[6][3], 0, 0, 0);
    acc[7][0] = __builtin_amdgcn_mfma_f32_16x16x32_bf16(a3, b0, acc[7][0], 0, 0, 0);
    acc[7][1] = __builtin_amdgcn_mfma_f32_16x16x32_bf16(a3, b1, acc[7][1], 0, 0, 0);
    acc[7][2] = __builtin_amdgcn_mfma_f32_16x16x32_bf16(a3, b2, acc[7][2], 0, 0, 0);
    acc[7][3] = __builtin_amdgcn_mfma_f32_16x16x32_bf16(a3, b3, acc[7][3], 0, 0, 0);
    __builtin_amdgcn_s_setprio(0);
    // counted wait for the NEXT tile's buffer (never 0 in steady state)
    if (t < NT - 1) {
      const int c = NT - 2 - t;
      if (c >= 2)      asm volatile("s_waitcnt vmcnt(8)" ::: "memory");
      else if (c == 1) asm volatile("s_waitcnt vmcnt(4)" ::: "memory");
      else             asm volatile("s_waitcnt vmcnt(0)" ::: "memory");
      __builtin_amdgcn_sched_barrier(0);
    }
    __builtin_amdgcn_s_barrier();
  }

  // ---- epilogue (+ optional fused softmax over each 64-col head chunk)
  const int orow = tm * BM + wr * 128;
  const int ocol = tn * BN + wc * 64;
  const bool do_sm = SOFTMAX && (tn * BN < 1536);
#pragma unroll
  for (int m = 0; m < 8; ++m) {
    if (do_sm) {
#pragma unroll
      for (int q = 0; q < 4; ++q) {
        float mx = fmaxf(fmaxf(acc[m][0][q], acc[m][1][q]),
                         fmaxf(acc[m][2][q], acc[m][3][q]));
#pragma unroll
        for (int s = 1; s <= 8; s <<= 1) mx = fmaxf(mx, __shfl_xor(mx, s, 64));
        float e0 = __expf(acc[m][0][q] - mx);
        float e1 = __expf(acc[m][1][q] - mx);
        float e2 = __expf(acc[m][2][q] - mx);
        float e3 = __expf(acc[m][3][q] - mx);
        float sum = e0 + e1 + e2 + e3;
#pragma unroll
        for (int s = 1; s <= 8; s <<= 1) sum += __shfl_xor(sum, s, 64);
        float inv = 1.0f / sum;
        acc[m][0][q] = e0 * inv; acc[m][1][q] = e1 * inv;
        acc[m][2][q] = e2 * inv; acc[m][3][q] = e3 * inv;
      }
    }
#pragma unroll
    for (int n = 0; n < 4; ++n) {
      const int col = ocol + n * 16 + lr;
      const float bv = BIAS ? bias[col] : 0.0f;
#pragma unroll
      for (int q = 0; q < 4; ++q) {
        const int row = orow + m * 16 + hi * 4 + q;
        const float v = acc[m][n][q] + bv;
        if (OUT_BF16) ((u16*)Cv)[(size_t)row * N + col] = f2b(v);
        else          ((float*)Cv)[(size_t)row * N + col] = v;
      }
    }
  }
}

// ---- context partials: partial[sp][bh][d][e] = sum_{n in split} k[n,d]*v[n,e] ----
#define NS 8
__global__ __launch_bounds__(256) void ctx_partial_kernel(const u16* __restrict__ qkv,
                                                          float* __restrict__ partial) {
  __shared__ u16 kT[64 * 136];
  __shared__ u16 vT[64 * 136];
  int bh = blockIdx.x / NS, sp = blockIdx.x % NS;
  int b = bh / 12, h = bh % 12;
  int tid = threadIdx.x, wave = tid >> 6, lane = tid & 63;
  int lr = lane & 15, lk = (lane >> 4) << 3;
  f32x4 acc[4] = {};
  int baseK = 768 + h * 64, baseV = 1536 + h * 64;

  for (int sub = 0; sub < 4; ++sub) {
    int nbase = b * 4096 + sp * 512 + sub * 128;
    __syncthreads();
#pragma unroll
    for (int it = 0; it < 4; ++it) {
      int s = it * 256 + tid;
      int n = s >> 3, c8 = (s & 7) * 8;
      u16x8 kv = *(const u16x8*)(qkv + (size_t)(nbase + n) * 2304 + baseK + c8);
      u16x8 vv = *(const u16x8*)(qkv + (size_t)(nbase + n) * 2304 + baseV + c8);
#pragma unroll
      for (int q = 0; q < 8; ++q) {
        kT[(c8 + q) * 136 + n] = kv[q];
        vT[(c8 + q) * 136 + n] = vv[q];
      }
    }
    __syncthreads();
#pragma unroll
    for (int ks = 0; ks < 4; ++ks) {
      bf16x8 af = *(const bf16x8*)&kT[(wave * 16 + lr) * 136 + ks * 32 + lk];
#pragma unroll
      for (int jt = 0; jt < 4; ++jt) {
        bf16x8 bfv = *(const bf16x8*)&vT[(jt * 16 + lr) * 136 + ks * 32 + lk];
        acc[jt] = __builtin_amdgcn_mfma_f32_16x16x32_bf16(af, bfv, acc[jt], 0, 0, 0);
      }
    }
  }
  float* dst = partial + ((size_t)sp * 96 + bh) * 4096;
#pragma unroll
  for (int jt = 0; jt < 4; ++jt)
#pragma unroll
    for (int q = 0; q < 4; ++q) {
      int d = wave * 16 + (lane >> 4) * 4 + q;
      int e = jt * 16 + lr;
      dst[d * 64 + e] = acc[jt][q];
    }
}

// ---- reduce partials -> ctxT[bh][e][d] bf16 ----
__global__ __launch_bounds__(256) void ctx_reduce_kernel(const float* __restrict__ partial,
                                                         u16* __restrict__ ctxT) {
  int idx = blockIdx.x * 256 + threadIdx.x;
  int bh = idx >> 12;
  int e = (idx >> 6) & 63, d = idx & 63;
  float s = 0.0f;
#pragma unroll
  for (int sp = 0; sp < NS; ++sp) s += partial[((size_t)sp * 96 + bh) * 4096 + d * 64 + e];
  ctxT[(size_t)bh * 4096 + e * 64 + d] = f2b(s);
}

// ---- attn[b*4096+n][h*64+e] = sum_d q[n,d]*ctx[d,e]  (bf16 out) ----
__global__ __launch_bounds__(256) void attn_kernel(const u16* __restrict__ qkv,
                                                   const u16* __restrict__ ctxT,
                                                   u16* __restrict__ attn) {
  __shared__ u16 qs[128 * 64];
  __shared__ u16 cs[64 * 64];
  int bh = blockIdx.x >> 5, nt = blockIdx.x & 31;
  int b = bh / 12, h = bh % 12;
  int tid = threadIdx.x, wave = tid >> 6, lane = tid & 63;
  int lr = lane & 15, lk = (lane >> 4) << 3;
  int row0 = b * 4096 + nt * 128;
#pragma unroll
  for (int it = 0; it < 4; ++it) {
    int u = it * 256 + tid;
    int n = u >> 3, c8 = (u & 7) * 8;
    gload_lds16(qkv + (size_t)(row0 + n) * 2304 + h * 64 + c8, &qs[(it * 256 + wave * 64) * 8]);
  }
#pragma unroll
  for (int it = 0; it < 2; ++it) {
    int u = it * 256 + tid;
    gload_lds16(ctxT + (size_t)bh * 4096 + u * 8, &cs[(it * 256 + wave * 64) * 8]);
  }
  __syncthreads();
  f32x4 acc[2][4] = {};
#pragma unroll
  for (int ks = 0; ks < 2; ++ks) {
    bf16x8 bv[4];
#pragma unroll
    for (int jt = 0; jt < 4; ++jt) bv[jt] = *(const bf16x8*)&cs[(jt * 16 + lr) * 64 + ks * 32 + lk];
#pragma unroll
    for (int i = 0; i < 2; ++i) {
      bf16x8 af = *(const bf16x8*)&qs[(wave * 32 + i * 16 + lr) * 64 + ks * 32 + lk];
#pragma unroll
      for (int jt = 0; jt < 4; ++jt)
        acc[i][jt] = __builtin_amdgcn_mfma_f32_16x16x32_bf16(af, bv[jt], acc[i][jt], 0, 0, 0);
    }
  }
#pragma unroll
  for (int i = 0; i < 2; ++i)
#pragma unroll
    for (int jt = 0; jt < 4; ++jt)
#pragma unroll
      for (int q = 0; q < 4; ++q) {
        int n = nt * 128 + wave * 32 + i * 16 + (lane >> 4) * 4 + q;
        int col = h * 64 + jt * 16 + lr;
        attn[(size_t)(b * 4096 + n) * 768 + col] = f2b(acc[i][jt][q]);
      }
}

extern "C" void kernel_launch(void* const* d_in, const int* in_sizes, int n_in,
                              void* d_out, int out_size, void* d_ws, size_t ws_size,
                              hipStream_t stream) {
  const float* x = (const float*)d_in[0];
  const float* Wqkv = (const float*)d_in[1];
  const float* Wproj = (const float*)d_in[2];
  const float* bproj = (const float*)d_in[3];
  float* out = (float*)d_out;
  char* ws = (char*)d_ws;

  u16* xb     = (u16*)(ws);                      // 32768*768*2   = 50331648
  u16* WqkvT  = (u16*)(ws + 50331648);           // 2304*768*2    = 3538944
  u16* WprojT = (u16*)(ws + 53870592);           // 768*768*2     = 1179648
  u16* qkv    = (u16*)(ws + 55050240);           // 32768*2304*2  = 150994944
  float* partial = (float*)(ws + 206045184);     // 8*96*4096*4   = 12582912
  u16* ctxT   = (u16*)(ws + 218628096);          // 96*4096*2     = 786432
  u16* attn   = (u16*)(ws + 219414528);          // 32768*768*2   = 50331648

  cast_x_kernel<<<2048, 256, 0, stream>>>(x, xb, (size_t)(32768ll * 768 / 8));
  transpose_cast_kernel<<<(768 / 32) * (2304 / 32), 256, 0, stream>>>(Wqkv, WqkvT, 768, 2304);
  transpose_cast_kernel<<<(768 / 32) * (768 / 32), 256, 0, stream>>>(Wproj, WprojT, 768, 768);

  // GEMM1: qkv = xb @ WqkvT^T, fused softmax on cols [0,1536)
  gemm256_kernel<true, false, true><<<(32768 / 256) * (2304 / 256), 512, 0, stream>>>(
      xb, WqkvT, (void*)qkv, nullptr, 32768, 2304, 768, 2304 / 256);

  ctx_partial_kernel<<<96 * NS, 256, 0, stream>>>(qkv, partial);
  ctx_reduce_kernel<<<(96 * 4096) / 256, 256, 0, stream>>>(partial, ctxT);

  attn_kernel<<<96 * 32, 256, 0, stream>>>(qkv, ctxT, attn);

  // GEMM3: out = attn @ WprojT^T + bias
  gemm256_kernel<false, true, false><<<(32768 / 256) * (768 / 256), 512, 0, stream>>>(
      attn, WprojT, (void*)out, bproj, 32768, 768, 768, 768 / 256);
}